// Round 1
// baseline (2230.081 us; speedup 1.0000x reference)
//
#include <hip/hip_runtime.h>
#include <math.h>

#define NN 50000
#define NE 320000

// ---------------------------------------------------------------------------
// Node projections: C = X @ W^T + b for W in {Wq,Wk,Wv,Ws}; mat chosen by
// blockIdx.y>>2, 64-col tile by blockIdx.y&3. Classic 64x64x16 fp32 tile,
// 256 threads, 4x4 micro-tile per thread.
// ---------------------------------------------------------------------------
__global__ __launch_bounds__(256)
void node_proj_kernel(const float* __restrict__ X,
                      const float* __restrict__ Wq, const float* __restrict__ bq,
                      const float* __restrict__ Wk, const float* __restrict__ bk,
                      const float* __restrict__ Wv, const float* __restrict__ bv,
                      const float* __restrict__ Ws, const float* __restrict__ bs,
                      float* __restrict__ qn, float* __restrict__ kn,
                      float* __restrict__ vn, float* __restrict__ outS)
{
    const int mat  = blockIdx.y >> 2;
    const int col0 = (blockIdx.y & 3) * 64;
    const int m0   = blockIdx.x * 64;

    const float* __restrict__ W;
    const float* __restrict__ bias;
    float* __restrict__ C;
    switch (mat) {
        case 0:  W = Wq; bias = bq; C = qn;   break;
        case 1:  W = Wk; bias = bk; C = kn;   break;
        case 2:  W = Wv; bias = bv; C = vn;   break;
        default: W = Ws; bias = bs; C = outS; break;
    }

    __shared__ float sA[16][68];   // [k][m], padded to keep 16B-aligned rows
    __shared__ float sB[16][68];   // [k][n]

    const int tid = threadIdx.x;
    const int tm  = tid >> 4;        // 0..15
    const int tn  = tid & 15;        // 0..15
    const int lm  = tid >> 2;        // 0..63 (row for loads)
    const int lq  = (tid & 3) * 4;   // k-quad offset for loads

    float acc[4][4] = {};

    for (int k0 = 0; k0 < 256; k0 += 16) {
        int row = m0 + lm;
        float4 a4 = make_float4(0.f, 0.f, 0.f, 0.f);
        if (row < NN) a4 = *(const float4*)(X + (size_t)row * 256 + k0 + lq);
        sA[lq + 0][lm] = a4.x; sA[lq + 1][lm] = a4.y;
        sA[lq + 2][lm] = a4.z; sA[lq + 3][lm] = a4.w;

        float4 b4 = *(const float4*)(W + (size_t)(col0 + lm) * 256 + k0 + lq);
        sB[lq + 0][lm] = b4.x; sB[lq + 1][lm] = b4.y;
        sB[lq + 2][lm] = b4.z; sB[lq + 3][lm] = b4.w;

        __syncthreads();
        #pragma unroll
        for (int kk = 0; kk < 16; ++kk) {
            float4 av  = *(const float4*)&sA[kk][tm * 4];
            float4 bv4 = *(const float4*)&sB[kk][tn * 4];
            float aa[4] = {av.x, av.y, av.z, av.w};
            float bb[4] = {bv4.x, bv4.y, bv4.z, bv4.w};
            #pragma unroll
            for (int i = 0; i < 4; ++i)
                #pragma unroll
                for (int j = 0; j < 4; ++j)
                    acc[i][j] = fmaf(aa[i], bb[j], acc[i][j]);
        }
        __syncthreads();
    }

    const float4 bias4 = *(const float4*)(bias + col0 + tn * 4);
    #pragma unroll
    for (int i = 0; i < 4; ++i) {
        int row = m0 + tm * 4 + i;
        if (row >= NN) continue;
        float4 o;
        o.x = acc[i][0] + bias4.x;
        o.y = acc[i][1] + bias4.y;
        o.z = acc[i][2] + bias4.z;
        o.w = acc[i][3] + bias4.w;
        *(float4*)(C + (size_t)row * 256 + col0 + tn * 4) = o;
    }
}

// ---------------------------------------------------------------------------
// Edge projection: ep = [cos(t*w_time+b_time) | edge_feats] @ We^T.
// Time-encoder columns (k<64) are computed on the fly in the A-loader, so
// e_attr is never materialized. K=192, same 64x64x16 tiling. E%64==0.
// ---------------------------------------------------------------------------
__global__ __launch_bounds__(256)
void edge_gemm_kernel(const float* __restrict__ efeat,
                      const float* __restrict__ tvals,
                      const float* __restrict__ w_time,
                      const float* __restrict__ b_time,
                      const float* __restrict__ We,
                      float* __restrict__ ep)
{
    const int col0 = blockIdx.y * 64;
    const int m0   = blockIdx.x * 64;

    __shared__ float sA[16][68];
    __shared__ float sB[16][68];

    const int tid = threadIdx.x;
    const int tm  = tid >> 4;
    const int tn  = tid & 15;
    const int lm  = tid >> 2;
    const int lq  = (tid & 3) * 4;

    const int   e  = m0 + lm;          // no guard: NE % 64 == 0
    const float tv = tvals[e];

    float acc[4][4] = {};

    for (int k0 = 0; k0 < 192; k0 += 16) {
        if (k0 < 64) {
            #pragma unroll
            for (int i = 0; i < 4; ++i) {
                int k = k0 + lq + i;
                sA[lq + i][lm] = cosf(fmaf(tv, w_time[k], b_time[k]));
            }
        } else {
            float4 a4 = *(const float4*)(efeat + (size_t)e * 128 + (k0 - 64) + lq);
            sA[lq + 0][lm] = a4.x; sA[lq + 1][lm] = a4.y;
            sA[lq + 2][lm] = a4.z; sA[lq + 3][lm] = a4.w;
        }
        float4 b4 = *(const float4*)(We + (size_t)(col0 + lm) * 192 + k0 + lq);
        sB[lq + 0][lm] = b4.x; sB[lq + 1][lm] = b4.y;
        sB[lq + 2][lm] = b4.z; sB[lq + 3][lm] = b4.w;

        __syncthreads();
        #pragma unroll
        for (int kk = 0; kk < 16; ++kk) {
            float4 av  = *(const float4*)&sA[kk][tm * 4];
            float4 bv4 = *(const float4*)&sB[kk][tn * 4];
            float aa[4] = {av.x, av.y, av.z, av.w};
            float bb[4] = {bv4.x, bv4.y, bv4.z, bv4.w};
            #pragma unroll
            for (int i = 0; i < 4; ++i)
                #pragma unroll
                for (int j = 0; j < 4; ++j)
                    acc[i][j] = fmaf(aa[i], bb[j], acc[i][j]);
        }
        __syncthreads();
    }

    #pragma unroll
    for (int i = 0; i < 4; ++i) {
        int row = m0 + tm * 4 + i;
        float4 o = make_float4(acc[i][0], acc[i][1], acc[i][2], acc[i][3]);
        *(float4*)(ep + (size_t)row * 256 + col0 + tn * 4) = o;
    }
}

// ---------------------------------------------------------------------------
// Edge pass 1: one wave per edge (4 edges / 256-thread block). Lane l owns
// channels 4l..4l+3 (head h = l>>3). alpha = q[dst]·(k[src]+ep)/sqrt(32);
// ea = exp(alpha) (max-shift skipped: mathematically identical ratio, alpha
// std ~1.4 so no overflow risk); atomicAdd ea into denom[dst][h].
// ---------------------------------------------------------------------------
__global__ __launch_bounds__(256)
void alpha_kernel(const int* __restrict__ et,
                  const float* __restrict__ qn, const float* __restrict__ kn,
                  const float* __restrict__ ep,
                  float* __restrict__ ea, float* __restrict__ denom)
{
    const int e    = blockIdx.x * 4 + (threadIdx.x >> 6);
    const int lane = threadIdx.x & 63;
    const int src  = et[e];
    const int dst  = et[NE + e];

    float4 q4 = *(const float4*)(qn + (size_t)dst * 256 + lane * 4);
    float4 k4 = *(const float4*)(kn + (size_t)src * 256 + lane * 4);
    float4 p4 = *(const float4*)(ep + (size_t)e   * 256 + lane * 4);

    float part = q4.x * (k4.x + p4.x) + q4.y * (k4.y + p4.y)
               + q4.z * (k4.z + p4.z) + q4.w * (k4.w + p4.w);
    part += __shfl_xor(part, 1);
    part += __shfl_xor(part, 2);
    part += __shfl_xor(part, 4);   // all 8 lanes of a head now hold alpha_h

    if ((lane & 7) == 0) {
        const int h  = lane >> 3;
        float eav = __expf(part * 0.17677669529663687f);  // 1/sqrt(32)
        ea[(size_t)e * 8 + h] = eav;
        atomicAdd(&denom[(size_t)dst * 8 + h], eav);
    }
}

// ---------------------------------------------------------------------------
// Edge pass 2: a = ea/denom[dst]; msg = a*(v[src]+ep); atomicAdd into out[dst].
// out already holds the skip connection (written by node_proj mat==3).
// ---------------------------------------------------------------------------
__global__ __launch_bounds__(256)
void agg_kernel(const int* __restrict__ et,
                const float* __restrict__ vn, const float* __restrict__ ep,
                const float* __restrict__ ea, const float* __restrict__ denom,
                float* __restrict__ out)
{
    const int e    = blockIdx.x * 4 + (threadIdx.x >> 6);
    const int lane = threadIdx.x & 63;
    const int src  = et[e];
    const int dst  = et[NE + e];
    const int h    = lane >> 3;

    float a = ea[(size_t)e * 8 + h] / (denom[(size_t)dst * 8 + h] + 1e-16f);

    float4 v4 = *(const float4*)(vn + (size_t)src * 256 + lane * 4);
    float4 p4 = *(const float4*)(ep + (size_t)e   * 256 + lane * 4);

    float* po = out + (size_t)dst * 256 + lane * 4;
    atomicAdd(po + 0, a * (v4.x + p4.x));
    atomicAdd(po + 1, a * (v4.y + p4.y));
    atomicAdd(po + 2, a * (v4.z + p4.z));
    atomicAdd(po + 3, a * (v4.w + p4.w));
}

// ---------------------------------------------------------------------------
extern "C" void kernel_launch(void* const* d_in, const int* in_sizes, int n_in,
                              void* d_out, int out_size, void* d_ws, size_t ws_size,
                              hipStream_t stream)
{
    const int*   et  = (const int*)  d_in[0];
    const float* ef  = (const float*)d_in[1];
    const float* tv  = (const float*)d_in[2];
    const float* nf  = (const float*)d_in[3];
    const float* w_t = (const float*)d_in[4];
    const float* b_t = (const float*)d_in[5];
    const float* Wq  = (const float*)d_in[6];
    const float* bq  = (const float*)d_in[7];
    const float* Wk  = (const float*)d_in[8];
    const float* bk  = (const float*)d_in[9];
    const float* Wv  = (const float*)d_in[10];
    const float* bv  = (const float*)d_in[11];
    const float* We  = (const float*)d_in[12];
    const float* Ws  = (const float*)d_in[13];
    const float* bs  = (const float*)d_in[14];
    float* out = (float*)d_out;

    // workspace layout (fp32): qn,kn,vn [NN,256]; ep [NE,256]; ea [NE,8]; denom [NN,8]
    float* qn    = (float*)d_ws;
    float* kn    = qn + (size_t)NN * 256;
    float* vn    = kn + (size_t)NN * 256;
    float* ep    = vn + (size_t)NN * 256;
    float* ea    = ep + (size_t)NE * 256;
    float* denom = ea + (size_t)NE * 8;
    size_t need  = (size_t)((char*)(denom + (size_t)NN * 8) - (char*)d_ws);
    if (ws_size < need) return;  // tell-tale: absmax will equal max|ref|

    hipMemsetAsync(denom, 0, (size_t)NN * 8 * sizeof(float), stream);

    node_proj_kernel<<<dim3((NN + 63) / 64, 16), 256, 0, stream>>>(
        nf, Wq, bq, Wk, bk, Wv, bv, Ws, bs, qn, kn, vn, out);

    edge_gemm_kernel<<<dim3(NE / 64, 4), 256, 0, stream>>>(
        ef, tv, w_t, b_t, We, ep);

    alpha_kernel<<<NE / 4, 256, 0, stream>>>(et, qn, kn, ep, ea, denom);

    agg_kernel<<<NE / 4, 256, 0, stream>>>(et, vn, ep, ea, denom, out);
}

// Round 2
// 1360.570 us; speedup vs baseline: 1.6391x; 1.6391x over previous
//
#include <hip/hip_runtime.h>
#include <math.h>

#define NN 50000
#define NE 320000

// ---------------------------------------------------------------------------
// Node projections: C = X @ W^T + b for W in {Wq,Wk,Wv,Ws}; mat chosen by
// blockIdx.y>>2, 64-col tile by blockIdx.y&3. 64x64x16 fp32 tile, 256 thr.
// ---------------------------------------------------------------------------
__global__ __launch_bounds__(256)
void node_proj_kernel(const float* __restrict__ X,
                      const float* __restrict__ Wq, const float* __restrict__ bq,
                      const float* __restrict__ Wk, const float* __restrict__ bk,
                      const float* __restrict__ Wv, const float* __restrict__ bv,
                      const float* __restrict__ Ws, const float* __restrict__ bs,
                      float* __restrict__ qn, float* __restrict__ kn,
                      float* __restrict__ vn, float* __restrict__ outS)
{
    const int mat  = blockIdx.y >> 2;
    const int col0 = (blockIdx.y & 3) * 64;
    const int m0   = blockIdx.x * 64;

    const float* __restrict__ W;
    const float* __restrict__ bias;
    float* __restrict__ C;
    switch (mat) {
        case 0:  W = Wq; bias = bq; C = qn;   break;
        case 1:  W = Wk; bias = bk; C = kn;   break;
        case 2:  W = Wv; bias = bv; C = vn;   break;
        default: W = Ws; bias = bs; C = outS; break;
    }

    __shared__ float sA[16][68];
    __shared__ float sB[16][68];

    const int tid = threadIdx.x;
    const int tm  = tid >> 4;
    const int tn  = tid & 15;
    const int lm  = tid >> 2;
    const int lq  = (tid & 3) * 4;

    float acc[4][4] = {};

    for (int k0 = 0; k0 < 256; k0 += 16) {
        int row = m0 + lm;
        float4 a4 = make_float4(0.f, 0.f, 0.f, 0.f);
        if (row < NN) a4 = *(const float4*)(X + (size_t)row * 256 + k0 + lq);
        sA[lq + 0][lm] = a4.x; sA[lq + 1][lm] = a4.y;
        sA[lq + 2][lm] = a4.z; sA[lq + 3][lm] = a4.w;

        float4 b4 = *(const float4*)(W + (size_t)(col0 + lm) * 256 + k0 + lq);
        sB[lq + 0][lm] = b4.x; sB[lq + 1][lm] = b4.y;
        sB[lq + 2][lm] = b4.z; sB[lq + 3][lm] = b4.w;

        __syncthreads();
        #pragma unroll
        for (int kk = 0; kk < 16; ++kk) {
            float4 av  = *(const float4*)&sA[kk][tm * 4];
            float4 bv4 = *(const float4*)&sB[kk][tn * 4];
            float aa[4] = {av.x, av.y, av.z, av.w};
            float bb[4] = {bv4.x, bv4.y, bv4.z, bv4.w};
            #pragma unroll
            for (int i = 0; i < 4; ++i)
                #pragma unroll
                for (int j = 0; j < 4; ++j)
                    acc[i][j] = fmaf(aa[i], bb[j], acc[i][j]);
        }
        __syncthreads();
    }

    const float4 bias4 = *(const float4*)(bias + col0 + tn * 4);
    #pragma unroll
    for (int i = 0; i < 4; ++i) {
        int row = m0 + tm * 4 + i;
        if (row >= NN) continue;
        float4 o;
        o.x = acc[i][0] + bias4.x;
        o.y = acc[i][1] + bias4.y;
        o.z = acc[i][2] + bias4.z;
        o.w = acc[i][3] + bias4.w;
        *(float4*)(C + (size_t)row * 256 + col0 + tn * 4) = o;
    }
}

// ---------------------------------------------------------------------------
// Edge projection: ep = [cos(t*w_time+b_time) | edge_feats] @ We^T.
// ---------------------------------------------------------------------------
__global__ __launch_bounds__(256)
void edge_gemm_kernel(const float* __restrict__ efeat,
                      const float* __restrict__ tvals,
                      const float* __restrict__ w_time,
                      const float* __restrict__ b_time,
                      const float* __restrict__ We,
                      float* __restrict__ ep)
{
    const int col0 = blockIdx.y * 64;
    const int m0   = blockIdx.x * 64;

    __shared__ float sA[16][68];
    __shared__ float sB[16][68];

    const int tid = threadIdx.x;
    const int tm  = tid >> 4;
    const int tn  = tid & 15;
    const int lm  = tid >> 2;
    const int lq  = (tid & 3) * 4;

    const int   e  = m0 + lm;          // NE % 64 == 0
    const float tv = tvals[e];

    float acc[4][4] = {};

    for (int k0 = 0; k0 < 192; k0 += 16) {
        if (k0 < 64) {
            #pragma unroll
            for (int i = 0; i < 4; ++i) {
                int k = k0 + lq + i;
                sA[lq + i][lm] = cosf(fmaf(tv, w_time[k], b_time[k]));
            }
        } else {
            float4 a4 = *(const float4*)(efeat + (size_t)e * 128 + (k0 - 64) + lq);
            sA[lq + 0][lm] = a4.x; sA[lq + 1][lm] = a4.y;
            sA[lq + 2][lm] = a4.z; sA[lq + 3][lm] = a4.w;
        }
        float4 b4 = *(const float4*)(We + (size_t)(col0 + lm) * 192 + k0 + lq);
        sB[lq + 0][lm] = b4.x; sB[lq + 1][lm] = b4.y;
        sB[lq + 2][lm] = b4.z; sB[lq + 3][lm] = b4.w;

        __syncthreads();
        #pragma unroll
        for (int kk = 0; kk < 16; ++kk) {
            float4 av  = *(const float4*)&sA[kk][tm * 4];
            float4 bv4 = *(const float4*)&sB[kk][tn * 4];
            float aa[4] = {av.x, av.y, av.z, av.w};
            float bb[4] = {bv4.x, bv4.y, bv4.z, bv4.w};
            #pragma unroll
            for (int i = 0; i < 4; ++i)
                #pragma unroll
                for (int j = 0; j < 4; ++j)
                    acc[i][j] = fmaf(aa[i], bb[j], acc[i][j]);
        }
        __syncthreads();
    }

    #pragma unroll
    for (int i = 0; i < 4; ++i) {
        int row = m0 + tm * 4 + i;
        float4 o = make_float4(acc[i][0], acc[i][1], acc[i][2], acc[i][3]);
        *(float4*)(ep + (size_t)row * 256 + col0 + tn * 4) = o;
    }
}

// ---------------------------------------------------------------------------
// CSR build: (1) histogram of dst, (2) single-block exclusive scan writing
// rowstart AND cursor, (3) scatter edge ids into elist via cursor atomics.
// ---------------------------------------------------------------------------
__global__ __launch_bounds__(256)
void deg_kernel(const int* __restrict__ et, int* __restrict__ deg)
{
    int e = blockIdx.x * 256 + threadIdx.x;
    if (e < NE) atomicAdd(&deg[et[NE + e]], 1);
}

__global__ __launch_bounds__(1024)
void scan_kernel(const int* __restrict__ deg,
                 int* __restrict__ rowstart, int* __restrict__ cursor)
{
    __shared__ int sums[1024];
    const int T  = 1024;
    const int CH = (NN + T - 1) / T;      // 49
    const int t    = threadIdx.x;
    const int base = t * CH;

    int s = 0;
    for (int i = 0; i < CH; ++i) {
        int idx = base + i;
        if (idx < NN) s += deg[idx];
    }
    sums[t] = s;
    __syncthreads();
    // Hillis-Steele inclusive scan in LDS
    for (int off = 1; off < T; off <<= 1) {
        int v = (t >= off) ? sums[t - off] : 0;
        __syncthreads();
        sums[t] += v;
        __syncthreads();
    }
    int run = (t == 0) ? 0 : sums[t - 1];
    for (int i = 0; i < CH; ++i) {
        int idx = base + i;
        if (idx < NN) {
            rowstart[idx] = run;
            cursor[idx]   = run;
            run += deg[idx];
        }
    }
    if (t == T - 1) rowstart[NN] = run;   // == NE
}

__global__ __launch_bounds__(256)
void scatter_kernel(const int* __restrict__ et,
                    int* __restrict__ cursor, int* __restrict__ elist)
{
    int e = blockIdx.x * 256 + threadIdx.x;
    if (e < NE) {
        int d   = et[NE + e];
        int pos = atomicAdd(&cursor[d], 1);
        elist[pos] = e;
    }
}

// ---------------------------------------------------------------------------
// Fused attention + aggregation + skip: one wave per dst node. Lane l owns
// channels 4l..4l+3 (head h = l>>3). q[dst] lives in registers across the
// edge loop. Per edge: alpha via intra-head shuffle reduce, ea = exp(alpha/
// sqrt(32)) (max-shift skipped: identical ratio, alpha is O(1)), accumulate
// ea*(v+ep) and the denominator in registers. One float4 RMW of out at end
// (out already holds the skip connection from node_proj). NO atomics.
// ---------------------------------------------------------------------------
__global__ __launch_bounds__(256)
void fused_agg_kernel(const int* __restrict__ et,
                      const int* __restrict__ rowstart,
                      const int* __restrict__ elist,
                      const float* __restrict__ qn, const float* __restrict__ kn,
                      const float* __restrict__ vn, const float* __restrict__ ep,
                      float* __restrict__ out)
{
    const int n = blockIdx.x * 4 + (threadIdx.x >> 6);
    if (n >= NN) return;                 // whole wave exits uniformly
    const int lane = threadIdx.x & 63;

    const float4 q4 = *(const float4*)(qn + (size_t)n * 256 + lane * 4);

    float acc0 = 0.f, acc1 = 0.f, acc2 = 0.f, acc3 = 0.f, accd = 0.f;

    const int s0 = rowstart[n];
    const int s1 = rowstart[n + 1];

    for (int i = s0; i < s1; ++i) {
        const int e   = elist[i];
        const int src = et[e];
        float4 k4 = *(const float4*)(kn + (size_t)src * 256 + lane * 4);
        float4 p4 = *(const float4*)(ep + (size_t)e   * 256 + lane * 4);
        float4 v4 = *(const float4*)(vn + (size_t)src * 256 + lane * 4);

        float part = q4.x * (k4.x + p4.x) + q4.y * (k4.y + p4.y)
                   + q4.z * (k4.z + p4.z) + q4.w * (k4.w + p4.w);
        part += __shfl_xor(part, 1);
        part += __shfl_xor(part, 2);
        part += __shfl_xor(part, 4);     // all 8 lanes of head h hold alpha_h

        float eav = __expf(part * 0.17677669529663687f);  // 1/sqrt(32)
        acc0 = fmaf(eav, v4.x + p4.x, acc0);
        acc1 = fmaf(eav, v4.y + p4.y, acc1);
        acc2 = fmaf(eav, v4.z + p4.z, acc2);
        acc3 = fmaf(eav, v4.w + p4.w, acc3);
        accd += eav;
    }

    const float inv = 1.f / (accd + 1e-16f);  // deg==0: acc*inv = 0*huge = 0
    float* po = out + (size_t)n * 256 + lane * 4;
    float4 o = *(const float4*)po;            // skip connection
    o.x = fmaf(acc0, inv, o.x);
    o.y = fmaf(acc1, inv, o.y);
    o.z = fmaf(acc2, inv, o.z);
    o.w = fmaf(acc3, inv, o.w);
    *(float4*)po = o;
}

// ---------------------------------------------------------------------------
extern "C" void kernel_launch(void* const* d_in, const int* in_sizes, int n_in,
                              void* d_out, int out_size, void* d_ws, size_t ws_size,
                              hipStream_t stream)
{
    const int*   et  = (const int*)  d_in[0];
    const float* ef  = (const float*)d_in[1];
    const float* tv  = (const float*)d_in[2];
    const float* nf  = (const float*)d_in[3];
    const float* w_t = (const float*)d_in[4];
    const float* b_t = (const float*)d_in[5];
    const float* Wq  = (const float*)d_in[6];
    const float* bq  = (const float*)d_in[7];
    const float* Wk  = (const float*)d_in[8];
    const float* bk  = (const float*)d_in[9];
    const float* Wv  = (const float*)d_in[10];
    const float* bv  = (const float*)d_in[11];
    const float* We  = (const float*)d_in[12];
    const float* Ws  = (const float*)d_in[13];
    const float* bs  = (const float*)d_in[14];
    float* out = (float*)d_out;

    // ws layout (fp32/int32): qn,kn,vn [NN,256]; ep [NE,256];
    // deg [NN]; rowstart [NN+1]; cursor [NN]; elist [NE]
    float* qn       = (float*)d_ws;
    float* kn       = qn + (size_t)NN * 256;
    float* vn       = kn + (size_t)NN * 256;
    float* ep       = vn + (size_t)NN * 256;
    int*   deg      = (int*)(ep + (size_t)NE * 256);
    int*   rowstart = deg + NN;
    int*   cursor   = rowstart + NN + 1;
    int*   elist    = cursor + NN;
    size_t need     = (size_t)((char*)(elist + NE) - (char*)d_ws);
    if (ws_size < need) return;

    hipMemsetAsync(deg, 0, (size_t)NN * sizeof(int), stream);

    node_proj_kernel<<<dim3((NN + 63) / 64, 16), 256, 0, stream>>>(
        nf, Wq, bq, Wk, bk, Wv, bv, Ws, bs, qn, kn, vn, out);

    edge_gemm_kernel<<<dim3(NE / 64, 4), 256, 0, stream>>>(
        ef, tv, w_t, b_t, We, ep);

    deg_kernel<<<(NE + 255) / 256, 256, 0, stream>>>(et, deg);
    scan_kernel<<<1, 1024, 0, stream>>>(deg, rowstart, cursor);
    scatter_kernel<<<(NE + 255) / 256, 256, 0, stream>>>(et, cursor, elist);

    fused_agg_kernel<<<(NN + 3) / 4, 256, 0, stream>>>(
        et, rowstart, elist, qn, kn, vn, ep, out);
}

// Round 3
// 982.048 us; speedup vs baseline: 2.2708x; 1.3854x over previous
//
#include <hip/hip_runtime.h>
#include <hip/hip_bf16.h>
#include <math.h>

#define NN 50000
#define NE 320000

typedef __attribute__((ext_vector_type(8))) short bf16x8;   // 8 bf16 (4 VGPRs)
typedef __attribute__((ext_vector_type(4))) float floatx4;  // MFMA C/D

static __device__ __forceinline__ unsigned pack2bf(float a, float b) {
    __hip_bfloat162 h = __float22bfloat162_rn(make_float2(a, b));
    return *reinterpret_cast<unsigned*>(&h);
}

// ---------------------------------------------------------------------------
// Node projections via MFMA: C = X @ W^T + b, W in {Wq,Wk,Wv,Ws}.
// blockIdx.y = ct in 0..7: mat = ct>>1, column half = ct&1.
// 128x128 tile, BK=32, 4 waves 2x2, each wave 64x64 (4x4 MFMA frags).
// Loaders convert fp32->bf16 on the fly (L3 absorbs col-tile re-reads).
// ---------------------------------------------------------------------------
__global__ __launch_bounds__(256)
void node_mfma_kernel(const float* __restrict__ X,
                      const float* __restrict__ Wq, const float* __restrict__ bq,
                      const float* __restrict__ Wk, const float* __restrict__ bk,
                      const float* __restrict__ Wv, const float* __restrict__ bv,
                      const float* __restrict__ Ws, const float* __restrict__ bs,
                      float* __restrict__ qn, float* __restrict__ kn,
                      float* __restrict__ vn, float* __restrict__ outS)
{
    const int m0  = blockIdx.x * 128;
    const int ct  = blockIdx.y;
    const int mat = ct >> 1, half = ct & 1;

    const float* __restrict__ W;
    const float* __restrict__ bias;
    float* __restrict__ C;
    switch (mat) {
        case 0:  W = Wq; bias = bq; C = qn;   break;
        case 1:  W = Wk; bias = bk; C = kn;   break;
        case 2:  W = Wv; bias = bv; C = vn;   break;
        default: W = Ws; bias = bs; C = outS; break;
    }
    W += (size_t)(half * 128) * 256;   // 128 output rows of this tile

    __shared__ __align__(16) short sA[128 * 32];
    __shared__ __align__(16) short sB[128 * 32];

    const int tid  = threadIdx.x;
    const int lane = tid & 63;
    const int wave = tid >> 6;
    const int wm   = (wave & 1) * 64;
    const int wn   = (wave >> 1) * 64;
    const int lr   = lane & 15;
    const int lq   = lane >> 4;

    floatx4 acc[4][4];
    #pragma unroll
    for (int i = 0; i < 4; ++i)
        #pragma unroll
        for (int j = 0; j < 4; ++j)
            acc[i][j] = (floatx4){0.f, 0.f, 0.f, 0.f};

    for (int k0 = 0; k0 < 256; k0 += 32) {
        #pragma unroll
        for (int r = 0; r < 4; ++r) {           // stage A: 128x32 fp32 -> bf16
            int vi = r * 256 + tid;
            int row = vi >> 3, cq = vi & 7;
            int grow = m0 + row;
            float4 a4 = make_float4(0.f, 0.f, 0.f, 0.f);
            if (grow < NN) a4 = *(const float4*)(X + (size_t)grow * 256 + k0 + cq * 4);
            unsigned* d = (unsigned*)&sA[row * 32 + cq * 4];
            d[0] = pack2bf(a4.x, a4.y);
            d[1] = pack2bf(a4.z, a4.w);
        }
        #pragma unroll
        for (int r = 0; r < 4; ++r) {           // stage B: 128x32 of W
            int vi = r * 256 + tid;
            int row = vi >> 3, cq = vi & 7;
            float4 b4 = *(const float4*)(W + (size_t)row * 256 + k0 + cq * 4);
            unsigned* d = (unsigned*)&sB[row * 32 + cq * 4];
            d[0] = pack2bf(b4.x, b4.y);
            d[1] = pack2bf(b4.z, b4.w);
        }
        __syncthreads();

        bf16x8 af[4], bfr[4];
        #pragma unroll
        for (int i = 0; i < 4; ++i)
            af[i] = *(const bf16x8*)&sA[(wm + i * 16 + lr) * 32 + lq * 8];
        #pragma unroll
        for (int j = 0; j < 4; ++j)
            bfr[j] = *(const bf16x8*)&sB[(wn + j * 16 + lr) * 32 + lq * 8];
        #pragma unroll
        for (int i = 0; i < 4; ++i)
            #pragma unroll
            for (int j = 0; j < 4; ++j)
                acc[i][j] = __builtin_amdgcn_mfma_f32_16x16x32_bf16(
                    af[i], bfr[j], acc[i][j], 0, 0, 0);
        __syncthreads();
    }

    const int colbase = half * 128;
    #pragma unroll
    for (int j = 0; j < 4; ++j) {
        int col = colbase + wn + j * 16 + lr;
        float bb = bias[col];
        #pragma unroll
        for (int i = 0; i < 4; ++i) {
            int rbase = m0 + wm + i * 16 + lq * 4;
            #pragma unroll
            for (int r = 0; r < 4; ++r) {
                int row = rbase + r;
                if (row < NN) C[(size_t)row * 256 + col] = acc[i][j][r] + bb;
            }
        }
    }
}

// ---------------------------------------------------------------------------
// Edge projection via MFMA: ep = [cos(t*w+b) | efeat] @ We^T. K=192.
// Time-encoder columns (k<64) computed in the A-loader. NE % 128 == 0.
// ---------------------------------------------------------------------------
__global__ __launch_bounds__(256)
void edge_mfma_kernel(const float* __restrict__ efeat,
                      const float* __restrict__ tvals,
                      const float* __restrict__ w_time,
                      const float* __restrict__ b_time,
                      const float* __restrict__ We,
                      float* __restrict__ ep)
{
    const int m0 = blockIdx.x * 128;
    const int n0 = blockIdx.y * 128;

    __shared__ __align__(16) short sA[128 * 32];
    __shared__ __align__(16) short sB[128 * 32];

    const int tid  = threadIdx.x;
    const int lane = tid & 63;
    const int wave = tid >> 6;
    const int wm   = (wave & 1) * 64;
    const int wn   = (wave >> 1) * 64;
    const int lr   = lane & 15;
    const int lq   = lane >> 4;

    floatx4 acc[4][4];
    #pragma unroll
    for (int i = 0; i < 4; ++i)
        #pragma unroll
        for (int j = 0; j < 4; ++j)
            acc[i][j] = (floatx4){0.f, 0.f, 0.f, 0.f};

    for (int k0 = 0; k0 < 192; k0 += 32) {
        #pragma unroll
        for (int r = 0; r < 4; ++r) {           // stage A
            int vi = r * 256 + tid;
            int row = vi >> 3, cq = vi & 7;
            float v0, v1, v2, v3;
            if (k0 < 64) {                      // time-encoder columns
                float tvv = tvals[m0 + row];
                int k = k0 + cq * 4;
                v0 = cosf(fmaf(tvv, w_time[k + 0], b_time[k + 0]));
                v1 = cosf(fmaf(tvv, w_time[k + 1], b_time[k + 1]));
                v2 = cosf(fmaf(tvv, w_time[k + 2], b_time[k + 2]));
                v3 = cosf(fmaf(tvv, w_time[k + 3], b_time[k + 3]));
            } else {
                float4 a4 = *(const float4*)(efeat + (size_t)(m0 + row) * 128
                                             + (k0 - 64) + cq * 4);
                v0 = a4.x; v1 = a4.y; v2 = a4.z; v3 = a4.w;
            }
            unsigned* d = (unsigned*)&sA[row * 32 + cq * 4];
            d[0] = pack2bf(v0, v1);
            d[1] = pack2bf(v2, v3);
        }
        #pragma unroll
        for (int r = 0; r < 4; ++r) {           // stage B: rows of We
            int vi = r * 256 + tid;
            int row = vi >> 3, cq = vi & 7;
            float4 b4 = *(const float4*)(We + (size_t)(n0 + row) * 192 + k0 + cq * 4);
            unsigned* d = (unsigned*)&sB[row * 32 + cq * 4];
            d[0] = pack2bf(b4.x, b4.y);
            d[1] = pack2bf(b4.z, b4.w);
        }
        __syncthreads();

        bf16x8 af[4], bfr[4];
        #pragma unroll
        for (int i = 0; i < 4; ++i)
            af[i] = *(const bf16x8*)&sA[(wm + i * 16 + lr) * 32 + lq * 8];
        #pragma unroll
        for (int j = 0; j < 4; ++j)
            bfr[j] = *(const bf16x8*)&sB[(wn + j * 16 + lr) * 32 + lq * 8];
        #pragma unroll
        for (int i = 0; i < 4; ++i)
            #pragma unroll
            for (int j = 0; j < 4; ++j)
                acc[i][j] = __builtin_amdgcn_mfma_f32_16x16x32_bf16(
                    af[i], bfr[j], acc[i][j], 0, 0, 0);
        __syncthreads();
    }

    #pragma unroll
    for (int j = 0; j < 4; ++j) {
        int col = n0 + wn + j * 16 + lr;
        #pragma unroll
        for (int i = 0; i < 4; ++i) {
            size_t rbase = m0 + wm + i * 16 + lq * 4;
            #pragma unroll
            for (int r = 0; r < 4; ++r)
                ep[(rbase + r) * 256 + col] = acc[i][j][r];
        }
    }
}

// ---------------------------------------------------------------------------
// CSR build: histogram, single-block scan, scatter.
// ---------------------------------------------------------------------------
__global__ __launch_bounds__(256)
void deg_kernel(const int* __restrict__ et, int* __restrict__ deg)
{
    int e = blockIdx.x * 256 + threadIdx.x;
    if (e < NE) atomicAdd(&deg[et[NE + e]], 1);
}

__global__ __launch_bounds__(1024)
void scan_kernel(const int* __restrict__ deg,
                 int* __restrict__ rowstart, int* __restrict__ cursor)
{
    __shared__ int sums[1024];
    const int T  = 1024;
    const int CH = (NN + T - 1) / T;
    const int t    = threadIdx.x;
    const int base = t * CH;

    int s = 0;
    for (int i = 0; i < CH; ++i) {
        int idx = base + i;
        if (idx < NN) s += deg[idx];
    }
    sums[t] = s;
    __syncthreads();
    for (int off = 1; off < T; off <<= 1) {
        int v = (t >= off) ? sums[t - off] : 0;
        __syncthreads();
        sums[t] += v;
        __syncthreads();
    }
    int run = (t == 0) ? 0 : sums[t - 1];
    for (int i = 0; i < CH; ++i) {
        int idx = base + i;
        if (idx < NN) {
            rowstart[idx] = run;
            cursor[idx]   = run;
            run += deg[idx];
        }
    }
    if (t == T - 1) rowstart[NN] = run;
}

__global__ __launch_bounds__(256)
void scatter_kernel(const int* __restrict__ et,
                    int* __restrict__ cursor, int* __restrict__ elist)
{
    int e = blockIdx.x * 256 + threadIdx.x;
    if (e < NE) {
        int d   = et[NE + e];
        int pos = atomicAdd(&cursor[d], 1);
        elist[pos] = e;
    }
}

// ---------------------------------------------------------------------------
// Fused attention + aggregation + skip: one wave per dst node, no atomics.
// ---------------------------------------------------------------------------
__global__ __launch_bounds__(256)
void fused_agg_kernel(const int* __restrict__ et,
                      const int* __restrict__ rowstart,
                      const int* __restrict__ elist,
                      const float* __restrict__ qn, const float* __restrict__ kn,
                      const float* __restrict__ vn, const float* __restrict__ ep,
                      float* __restrict__ out)
{
    const int n = blockIdx.x * 4 + (threadIdx.x >> 6);
    if (n >= NN) return;
    const int lane = threadIdx.x & 63;

    const float4 q4 = *(const float4*)(qn + (size_t)n * 256 + lane * 4);

    float acc0 = 0.f, acc1 = 0.f, acc2 = 0.f, acc3 = 0.f, accd = 0.f;

    const int s0 = rowstart[n];
    const int s1 = rowstart[n + 1];

    for (int i = s0; i < s1; ++i) {
        const int e   = elist[i];
        const int src = et[e];
        float4 k4 = *(const float4*)(kn + (size_t)src * 256 + lane * 4);
        float4 p4 = *(const float4*)(ep + (size_t)e   * 256 + lane * 4);
        float4 v4 = *(const float4*)(vn + (size_t)src * 256 + lane * 4);

        float part = q4.x * (k4.x + p4.x) + q4.y * (k4.y + p4.y)
                   + q4.z * (k4.z + p4.z) + q4.w * (k4.w + p4.w);
        part += __shfl_xor(part, 1);
        part += __shfl_xor(part, 2);
        part += __shfl_xor(part, 4);

        float eav = __expf(part * 0.17677669529663687f);
        acc0 = fmaf(eav, v4.x + p4.x, acc0);
        acc1 = fmaf(eav, v4.y + p4.y, acc1);
        acc2 = fmaf(eav, v4.z + p4.z, acc2);
        acc3 = fmaf(eav, v4.w + p4.w, acc3);
        accd += eav;
    }

    const float inv = 1.f / (accd + 1e-16f);
    float* po = out + (size_t)n * 256 + lane * 4;
    float4 o = *(const float4*)po;
    o.x = fmaf(acc0, inv, o.x);
    o.y = fmaf(acc1, inv, o.y);
    o.z = fmaf(acc2, inv, o.z);
    o.w = fmaf(acc3, inv, o.w);
    *(float4*)po = o;
}

// ---------------------------------------------------------------------------
extern "C" void kernel_launch(void* const* d_in, const int* in_sizes, int n_in,
                              void* d_out, int out_size, void* d_ws, size_t ws_size,
                              hipStream_t stream)
{
    const int*   et  = (const int*)  d_in[0];
    const float* ef  = (const float*)d_in[1];
    const float* tv  = (const float*)d_in[2];
    const float* nf  = (const float*)d_in[3];
    const float* w_t = (const float*)d_in[4];
    const float* b_t = (const float*)d_in[5];
    const float* Wq  = (const float*)d_in[6];
    const float* bq  = (const float*)d_in[7];
    const float* Wk  = (const float*)d_in[8];
    const float* bk  = (const float*)d_in[9];
    const float* Wv  = (const float*)d_in[10];
    const float* bv  = (const float*)d_in[11];
    const float* We  = (const float*)d_in[12];
    const float* Ws  = (const float*)d_in[13];
    const float* bs  = (const float*)d_in[14];
    float* out = (float*)d_out;

    float* qn       = (float*)d_ws;
    float* kn       = qn + (size_t)NN * 256;
    float* vn       = kn + (size_t)NN * 256;
    float* ep       = vn + (size_t)NN * 256;
    int*   deg      = (int*)(ep + (size_t)NE * 256);
    int*   rowstart = deg + NN;
    int*   cursor   = rowstart + NN + 1;
    int*   elist    = cursor + NN;
    size_t need     = (size_t)((char*)(elist + NE) - (char*)d_ws);
    if (ws_size < need) return;

    hipMemsetAsync(deg, 0, (size_t)NN * sizeof(int), stream);

    node_mfma_kernel<<<dim3((NN + 127) / 128, 8), 256, 0, stream>>>(
        nf, Wq, bq, Wk, bk, Wv, bv, Ws, bs, qn, kn, vn, out);

    edge_mfma_kernel<<<dim3(NE / 128, 2), 256, 0, stream>>>(
        ef, tv, w_t, b_t, We, ep);

    deg_kernel<<<(NE + 255) / 256, 256, 0, stream>>>(et, deg);
    scan_kernel<<<1, 1024, 0, stream>>>(deg, rowstart, cursor);
    scatter_kernel<<<(NE + 255) / 256, 256, 0, stream>>>(et, cursor, elist);

    fused_agg_kernel<<<(NN + 3) / 4, 256, 0, stream>>>(
        et, rowstart, elist, qn, kn, vn, ep, out);
}

// Round 4
// 867.239 us; speedup vs baseline: 2.5715x; 1.1324x over previous
//
#include <hip/hip_runtime.h>
#include <hip/hip_bf16.h>
#include <math.h>

#define NN 50000
#define NE 320000

typedef __attribute__((ext_vector_type(8))) short bf16x8;   // 8 bf16 (4 VGPRs)
typedef __attribute__((ext_vector_type(4))) float floatx4;  // MFMA C/D

static __device__ __forceinline__ unsigned pack2bf(float a, float b) {
    __hip_bfloat162 h = __float22bfloat162_rn(make_float2(a, b));
    return *reinterpret_cast<unsigned*>(&h);
}
static __device__ __forceinline__ unsigned short f2bf(float x) {
    __hip_bfloat16 h = __float2bfloat16(x);
    return *reinterpret_cast<unsigned short*>(&h);
}
static __device__ __forceinline__ float bf2f(unsigned short u) {
    return __uint_as_float(((unsigned)u) << 16);
}

// ---------------------------------------------------------------------------
// Node projections via MFMA: C = X @ W^T + b, W in {Wq,Wk,Wv,Ws}.
// blockIdx.y = ct: mat = ct>>1, column half = ct&1. 128x128 tile, BK=32,
// 4 waves 2x2. q/k/v outputs stored bf16; skip (mat 3) fp32 into d_out.
// Epilogue goes through LDS for fully-coalesced 16B/lane stores.
// ---------------------------------------------------------------------------
__global__ __launch_bounds__(256)
void node_mfma_kernel(const float* __restrict__ X,
                      const float* __restrict__ Wq, const float* __restrict__ bq,
                      const float* __restrict__ Wk, const float* __restrict__ bk,
                      const float* __restrict__ Wv, const float* __restrict__ bv,
                      const float* __restrict__ Ws, const float* __restrict__ bs,
                      unsigned short* __restrict__ qb,
                      unsigned short* __restrict__ kb,
                      unsigned short* __restrict__ vb,
                      float* __restrict__ outS)
{
    const int m0  = blockIdx.x * 128;
    const int ct  = blockIdx.y;
    const int mat = ct >> 1, half = ct & 1;
    const int colbase = half * 128;

    const float* __restrict__ W;
    const float* __restrict__ bias;
    switch (mat) {
        case 0:  W = Wq; bias = bq; break;
        case 1:  W = Wk; bias = bk; break;
        case 2:  W = Wv; bias = bv; break;
        default: W = Ws; bias = bs; break;
    }
    W += (size_t)colbase * 256;

    __shared__ __align__(16) unsigned char smem[16384];
    short* sA = (short*)smem;            // [128*32]
    short* sB = (short*)(smem + 8192);   // [128*32]

    const int tid  = threadIdx.x;
    const int lane = tid & 63;
    const int wave = tid >> 6;
    const int wm   = (wave & 1) * 64;
    const int wn   = (wave >> 1) * 64;
    const int lr   = lane & 15;
    const int lq   = lane >> 4;

    floatx4 acc[4][4];
    #pragma unroll
    for (int i = 0; i < 4; ++i)
        #pragma unroll
        for (int j = 0; j < 4; ++j)
            acc[i][j] = (floatx4){0.f, 0.f, 0.f, 0.f};

    for (int k0 = 0; k0 < 256; k0 += 32) {
        #pragma unroll
        for (int r = 0; r < 4; ++r) {
            int vi = r * 256 + tid;
            int row = vi >> 3, cq = vi & 7;
            int grow = m0 + row;
            float4 a4 = make_float4(0.f, 0.f, 0.f, 0.f);
            if (grow < NN) a4 = *(const float4*)(X + (size_t)grow * 256 + k0 + cq * 4);
            unsigned* d = (unsigned*)&sA[row * 32 + cq * 4];
            d[0] = pack2bf(a4.x, a4.y);
            d[1] = pack2bf(a4.z, a4.w);
        }
        #pragma unroll
        for (int r = 0; r < 4; ++r) {
            int vi = r * 256 + tid;
            int row = vi >> 3, cq = vi & 7;
            float4 b4 = *(const float4*)(W + (size_t)row * 256 + k0 + cq * 4);
            unsigned* d = (unsigned*)&sB[row * 32 + cq * 4];
            d[0] = pack2bf(b4.x, b4.y);
            d[1] = pack2bf(b4.z, b4.w);
        }
        __syncthreads();

        bf16x8 af[4], bfr[4];
        #pragma unroll
        for (int i = 0; i < 4; ++i)
            af[i] = *(const bf16x8*)&sA[(wm + i * 16 + lr) * 32 + lq * 8];
        #pragma unroll
        for (int j = 0; j < 4; ++j)
            bfr[j] = *(const bf16x8*)&sB[(wn + j * 16 + lr) * 32 + lq * 8];
        #pragma unroll
        for (int i = 0; i < 4; ++i)
            #pragma unroll
            for (int j = 0; j < 4; ++j)
                acc[i][j] = __builtin_amdgcn_mfma_f32_16x16x32_bf16(
                    af[i], bfr[j], acc[i][j], 0, 0, 0);
        __syncthreads();
    }

    if (mat < 3) {
        unsigned short* __restrict__ Cb = (mat == 0) ? qb : (mat == 1) ? kb : vb;
        unsigned short* sOut = (unsigned short*)smem;   // [32][136]
        for (int ch = 0; ch < 4; ++ch) {
            __syncthreads();
            if ((ch >> 1) == (wave & 1)) {
                int ibase = (ch & 1) * 2;
                #pragma unroll
                for (int ii = 0; ii < 2; ++ii) {
                    int i = ibase + ii;
                    #pragma unroll
                    for (int j = 0; j < 4; ++j) {
                        int col = wn + j * 16 + lr;
                        float bb = bias[colbase + col];
                        #pragma unroll
                        for (int r = 0; r < 4; ++r) {
                            int rowc = ii * 16 + lq * 4 + r;
                            sOut[rowc * 136 + col] = f2bf(acc[i][j][r] + bb);
                        }
                    }
                }
            }
            __syncthreads();
            #pragma unroll
            for (int p = 0; p < 2; ++p) {
                int rowc = p * 16 + (tid >> 4);
                int off  = (tid & 15) * 8;
                int grow = m0 + ch * 32 + rowc;
                if (grow < NN) {
                    uint4 u = *(const uint4*)&sOut[rowc * 136 + off];
                    *(uint4*)&Cb[(size_t)grow * 256 + colbase + off] = u;
                }
            }
        }
    } else {
        float* sOutF = (float*)smem;    // [16][132]
        for (int ch = 0; ch < 8; ++ch) {
            __syncthreads();
            if ((ch >> 2) == (wave & 1)) {
                int i = ch & 3;
                #pragma unroll
                for (int j = 0; j < 4; ++j) {
                    int col = wn + j * 16 + lr;
                    float bb = bias[colbase + col];
                    #pragma unroll
                    for (int r = 0; r < 4; ++r) {
                        int rowc = lq * 4 + r;
                        sOutF[rowc * 132 + col] = acc[i][j][r] + bb;
                    }
                }
            }
            __syncthreads();
            #pragma unroll
            for (int p = 0; p < 2; ++p) {
                int rowc = p * 8 + (tid >> 5);
                int off  = (tid & 31) * 4;
                int grow = m0 + ch * 16 + rowc;
                if (grow < NN) {
                    float4 f = *(const float4*)&sOutF[rowc * 132 + off];
                    *(float4*)&outS[(size_t)grow * 256 + colbase + off] = f;
                }
            }
        }
    }
}

// ---------------------------------------------------------------------------
// Edge projection via MFMA: ep = [cos(t*w+b) | efeat] @ We^T, output bf16.
// K=192, time-encoder columns computed in the A-loader. NE % 128 == 0.
// ---------------------------------------------------------------------------
__global__ __launch_bounds__(256)
void edge_mfma_kernel(const float* __restrict__ efeat,
                      const float* __restrict__ tvals,
                      const float* __restrict__ w_time,
                      const float* __restrict__ b_time,
                      const float* __restrict__ We,
                      unsigned short* __restrict__ epb)
{
    const int m0 = blockIdx.x * 128;
    const int n0 = blockIdx.y * 128;

    __shared__ __align__(16) unsigned char smem[16384];
    short* sA = (short*)smem;
    short* sB = (short*)(smem + 8192);

    const int tid  = threadIdx.x;
    const int lane = tid & 63;
    const int wave = tid >> 6;
    const int wm   = (wave & 1) * 64;
    const int wn   = (wave >> 1) * 64;
    const int lr   = lane & 15;
    const int lq   = lane >> 4;

    floatx4 acc[4][4];
    #pragma unroll
    for (int i = 0; i < 4; ++i)
        #pragma unroll
        for (int j = 0; j < 4; ++j)
            acc[i][j] = (floatx4){0.f, 0.f, 0.f, 0.f};

    for (int k0 = 0; k0 < 192; k0 += 32) {
        #pragma unroll
        for (int r = 0; r < 4; ++r) {
            int vi = r * 256 + tid;
            int row = vi >> 3, cq = vi & 7;
            float v0, v1, v2, v3;
            if (k0 < 64) {
                float tvv = tvals[m0 + row];
                int k = k0 + cq * 4;
                v0 = cosf(fmaf(tvv, w_time[k + 0], b_time[k + 0]));
                v1 = cosf(fmaf(tvv, w_time[k + 1], b_time[k + 1]));
                v2 = cosf(fmaf(tvv, w_time[k + 2], b_time[k + 2]));
                v3 = cosf(fmaf(tvv, w_time[k + 3], b_time[k + 3]));
            } else {
                float4 a4 = *(const float4*)(efeat + (size_t)(m0 + row) * 128
                                             + (k0 - 64) + cq * 4);
                v0 = a4.x; v1 = a4.y; v2 = a4.z; v3 = a4.w;
            }
            unsigned* d = (unsigned*)&sA[row * 32 + cq * 4];
            d[0] = pack2bf(v0, v1);
            d[1] = pack2bf(v2, v3);
        }
        #pragma unroll
        for (int r = 0; r < 4; ++r) {
            int vi = r * 256 + tid;
            int row = vi >> 3, cq = vi & 7;
            float4 b4 = *(const float4*)(We + (size_t)(n0 + row) * 192 + k0 + cq * 4);
            unsigned* d = (unsigned*)&sB[row * 32 + cq * 4];
            d[0] = pack2bf(b4.x, b4.y);
            d[1] = pack2bf(b4.z, b4.w);
        }
        __syncthreads();

        bf16x8 af[4], bfr[4];
        #pragma unroll
        for (int i = 0; i < 4; ++i)
            af[i] = *(const bf16x8*)&sA[(wm + i * 16 + lr) * 32 + lq * 8];
        #pragma unroll
        for (int j = 0; j < 4; ++j)
            bfr[j] = *(const bf16x8*)&sB[(wn + j * 16 + lr) * 32 + lq * 8];
        #pragma unroll
        for (int i = 0; i < 4; ++i)
            #pragma unroll
            for (int j = 0; j < 4; ++j)
                acc[i][j] = __builtin_amdgcn_mfma_f32_16x16x32_bf16(
                    af[i], bfr[j], acc[i][j], 0, 0, 0);
        __syncthreads();
    }

    unsigned short* sOut = (unsigned short*)smem;   // [32][136]
    for (int ch = 0; ch < 4; ++ch) {
        __syncthreads();
        if ((ch >> 1) == (wave & 1)) {
            int ibase = (ch & 1) * 2;
            #pragma unroll
            for (int ii = 0; ii < 2; ++ii) {
                int i = ibase + ii;
                #pragma unroll
                for (int j = 0; j < 4; ++j) {
                    int col = wn + j * 16 + lr;
                    #pragma unroll
                    for (int r = 0; r < 4; ++r) {
                        int rowc = ii * 16 + lq * 4 + r;
                        sOut[rowc * 136 + col] = f2bf(acc[i][j][r]);
                    }
                }
            }
        }
        __syncthreads();
        #pragma unroll
        for (int p = 0; p < 2; ++p) {
            int rowc = p * 16 + (tid >> 4);
            int off  = (tid & 15) * 8;
            int grow = m0 + ch * 32 + rowc;
            uint4 u = *(const uint4*)&sOut[rowc * 136 + off];
            *(uint4*)&epb[(size_t)grow * 256 + n0 + off] = u;
        }
    }
}

// ---------------------------------------------------------------------------
// CSR build: histogram, single-block scan, scatter (also pre-gathers src).
// ---------------------------------------------------------------------------
__global__ __launch_bounds__(256)
void deg_kernel(const int* __restrict__ et, int* __restrict__ deg)
{
    int e = blockIdx.x * 256 + threadIdx.x;
    if (e < NE) atomicAdd(&deg[et[NE + e]], 1);
}

__global__ __launch_bounds__(1024)
void scan_kernel(const int* __restrict__ deg,
                 int* __restrict__ rowstart, int* __restrict__ cursor)
{
    __shared__ int sums[1024];
    const int T  = 1024;
    const int CH = (NN + T - 1) / T;
    const int t    = threadIdx.x;
    const int base = t * CH;

    int s = 0;
    for (int i = 0; i < CH; ++i) {
        int idx = base + i;
        if (idx < NN) s += deg[idx];
    }
    sums[t] = s;
    __syncthreads();
    for (int off = 1; off < T; off <<= 1) {
        int v = (t >= off) ? sums[t - off] : 0;
        __syncthreads();
        sums[t] += v;
        __syncthreads();
    }
    int run = (t == 0) ? 0 : sums[t - 1];
    for (int i = 0; i < CH; ++i) {
        int idx = base + i;
        if (idx < NN) {
            rowstart[idx] = run;
            cursor[idx]   = run;
            run += deg[idx];
        }
    }
    if (t == T - 1) rowstart[NN] = run;
}

__global__ __launch_bounds__(256)
void scatter_kernel(const int* __restrict__ et,
                    int* __restrict__ cursor,
                    int* __restrict__ elist, int* __restrict__ slist)
{
    int e = blockIdx.x * 256 + threadIdx.x;
    if (e < NE) {
        int d   = et[NE + e];
        int pos = atomicAdd(&cursor[d], 1);
        elist[pos] = e;
        slist[pos] = et[e];
    }
}

// ---------------------------------------------------------------------------
// Fused attention + aggregation + skip: one wave per dst node, bf16 gathers
// (8 B/lane, 512 B/row), fp32 math, no atomics.
// ---------------------------------------------------------------------------
__global__ __launch_bounds__(256)
void fused_agg_kernel(const int* __restrict__ slist,
                      const int* __restrict__ rowstart,
                      const int* __restrict__ elist,
                      const unsigned short* __restrict__ qb,
                      const unsigned short* __restrict__ kb,
                      const unsigned short* __restrict__ vb,
                      const unsigned short* __restrict__ epb,
                      float* __restrict__ out)
{
    const int n = blockIdx.x * 4 + (threadIdx.x >> 6);
    if (n >= NN) return;
    const int lane = threadIdx.x & 63;

    ushort4 qu = *(const ushort4*)(qb + (size_t)n * 256 + lane * 4);
    const float q0 = bf2f(qu.x), q1 = bf2f(qu.y), q2 = bf2f(qu.z), q3 = bf2f(qu.w);

    float acc0 = 0.f, acc1 = 0.f, acc2 = 0.f, acc3 = 0.f, accd = 0.f;

    const int s0 = rowstart[n];
    const int s1 = rowstart[n + 1];

    for (int i = s0; i < s1; ++i) {
        const int e   = elist[i];
        const int src = slist[i];
        ushort4 ku = *(const ushort4*)(kb  + (size_t)src * 256 + lane * 4);
        ushort4 pu = *(const ushort4*)(epb + (size_t)e   * 256 + lane * 4);
        ushort4 vu = *(const ushort4*)(vb  + (size_t)src * 256 + lane * 4);

        float kp0 = bf2f(ku.x) + bf2f(pu.x);
        float kp1 = bf2f(ku.y) + bf2f(pu.y);
        float kp2 = bf2f(ku.z) + bf2f(pu.z);
        float kp3 = bf2f(ku.w) + bf2f(pu.w);

        float part = q0 * kp0 + q1 * kp1 + q2 * kp2 + q3 * kp3;
        part += __shfl_xor(part, 1);
        part += __shfl_xor(part, 2);
        part += __shfl_xor(part, 4);

        float eav = __expf(part * 0.17677669529663687f);  // 1/sqrt(32)
        acc0 = fmaf(eav, bf2f(vu.x) + bf2f(pu.x), acc0);
        acc1 = fmaf(eav, bf2f(vu.y) + bf2f(pu.y), acc1);
        acc2 = fmaf(eav, bf2f(vu.z) + bf2f(pu.z), acc2);
        acc3 = fmaf(eav, bf2f(vu.w) + bf2f(pu.w), acc3);
        accd += eav;
    }

    const float inv = 1.f / (accd + 1e-16f);
    float* po = out + (size_t)n * 256 + lane * 4;
    float4 o = *(const float4*)po;
    o.x = fmaf(acc0, inv, o.x);
    o.y = fmaf(acc1, inv, o.y);
    o.z = fmaf(acc2, inv, o.z);
    o.w = fmaf(acc3, inv, o.w);
    *(float4*)po = o;
}

// ---------------------------------------------------------------------------
extern "C" void kernel_launch(void* const* d_in, const int* in_sizes, int n_in,
                              void* d_out, int out_size, void* d_ws, size_t ws_size,
                              hipStream_t stream)
{
    const int*   et  = (const int*)  d_in[0];
    const float* ef  = (const float*)d_in[1];
    const float* tv  = (const float*)d_in[2];
    const float* nf  = (const float*)d_in[3];
    const float* w_t = (const float*)d_in[4];
    const float* b_t = (const float*)d_in[5];
    const float* Wq  = (const float*)d_in[6];
    const float* bq  = (const float*)d_in[7];
    const float* Wk  = (const float*)d_in[8];
    const float* bk  = (const float*)d_in[9];
    const float* Wv  = (const float*)d_in[10];
    const float* bv  = (const float*)d_in[11];
    const float* We  = (const float*)d_in[12];
    const float* Ws  = (const float*)d_in[13];
    const float* bs  = (const float*)d_in[14];
    float* out = (float*)d_out;

    // ws layout: qb,kb,vb [NN,256] bf16; epb [NE,256] bf16; ints.
    unsigned short* qb  = (unsigned short*)d_ws;
    unsigned short* kb  = qb + (size_t)NN * 256;
    unsigned short* vb  = kb + (size_t)NN * 256;
    unsigned short* epb = vb + (size_t)NN * 256;
    int* deg      = (int*)(epb + (size_t)NE * 256);
    int* rowstart = deg + NN;
    int* cursor   = rowstart + NN + 1;
    int* elist    = cursor + NN;
    int* slist    = elist + NE;
    size_t need   = (size_t)((char*)(slist + NE) - (char*)d_ws);
    if (ws_size < need) return;

    hipMemsetAsync(deg, 0, (size_t)NN * sizeof(int), stream);

    node_mfma_kernel<<<dim3((NN + 127) / 128, 8), 256, 0, stream>>>(
        nf, Wq, bq, Wk, bk, Wv, bv, Ws, bs, qb, kb, vb, out);

    edge_mfma_kernel<<<dim3(NE / 128, 2), 256, 0, stream>>>(
        ef, tv, w_t, b_t, We, epb);

    deg_kernel<<<(NE + 255) / 256, 256, 0, stream>>>(et, deg);
    scan_kernel<<<1, 1024, 0, stream>>>(deg, rowstart, cursor);
    scatter_kernel<<<(NE + 255) / 256, 256, 0, stream>>>(et, cursor, elist, slist);

    fused_agg_kernel<<<(NN + 3) / 4, 256, 0, stream>>>(
        slist, rowstart, elist, qb, kb, vb, epb, out);
}

// Round 5
// 773.998 us; speedup vs baseline: 2.8812x; 1.1205x over previous
//
#include <hip/hip_runtime.h>
#include <hip/hip_bf16.h>
#include <math.h>

#define NN 50000
#define NE 320000

typedef __attribute__((ext_vector_type(8))) short bf16x8;   // 8 bf16 (4 VGPRs)
typedef __attribute__((ext_vector_type(4))) float floatx4;  // MFMA C/D

static __device__ __forceinline__ unsigned pack2bf(float a, float b) {
    __hip_bfloat162 h = __float22bfloat162_rn(make_float2(a, b));
    return *reinterpret_cast<unsigned*>(&h);
}
static __device__ __forceinline__ unsigned short f2bf(float x) {
    __hip_bfloat16 h = __float2bfloat16(x);
    return *reinterpret_cast<unsigned short*>(&h);
}
static __device__ __forceinline__ float bf2f(unsigned short u) {
    return __uint_as_float(((unsigned)u) << 16);
}
// async global->LDS, 16B per lane; lds dest = wave-uniform base + lane*16
static __device__ __forceinline__ void gload_lds16(const void* g, void* l) {
    __builtin_amdgcn_global_load_lds(
        (const __attribute__((address_space(1))) void*)g,
        (__attribute__((address_space(3))) void*)l, 16, 0, 0);
}

// ---------------------------------------------------------------------------
// fp32 -> bf16 streaming convert, 8 elems/thread. n8 = n/8.
// ---------------------------------------------------------------------------
__global__ __launch_bounds__(256)
void cvt_bf16_kernel(const float* __restrict__ in,
                     unsigned short* __restrict__ out, int n8)
{
    int t = blockIdx.x * 256 + threadIdx.x;
    if (t >= n8) return;
    const float4* p = (const float4*)in + (size_t)t * 2;
    float4 a = p[0], b = p[1];
    uint4 u;
    u.x = pack2bf(a.x, a.y); u.y = pack2bf(a.z, a.w);
    u.z = pack2bf(b.x, b.y); u.w = pack2bf(b.z, b.w);
    ((uint4*)out)[t] = u;
}

// ---------------------------------------------------------------------------
// e_attr bf16 [E,192]: cols 0..63 = cos(t*w+b)  (8 threads/row, 8 cols each)
// ---------------------------------------------------------------------------
__global__ __launch_bounds__(256)
void tf_kernel(const float* __restrict__ tvals,
               const float* __restrict__ w_time,
               const float* __restrict__ b_time,
               unsigned short* __restrict__ eab)
{
    int t = blockIdx.x * 256 + threadIdx.x;   // NE*8 threads
    int e = t >> 3, part = t & 7;
    if (e >= NE) return;
    float tv = tvals[e];
    int k = part * 8;
    float v[8];
    #pragma unroll
    for (int i = 0; i < 8; ++i)
        v[i] = cosf(fmaf(tv, w_time[k + i], b_time[k + i]));
    uint4 u;
    u.x = pack2bf(v[0], v[1]); u.y = pack2bf(v[2], v[3]);
    u.z = pack2bf(v[4], v[5]); u.w = pack2bf(v[6], v[7]);
    *(uint4*)(eab + (size_t)e * 192 + k) = u;
}

// cols 64..191 = bf16(efeat)  (16 threads/row, 8 cols each)
__global__ __launch_bounds__(256)
void efcvt_kernel(const float* __restrict__ efeat,
                  unsigned short* __restrict__ eab)
{
    int t = blockIdx.x * 256 + threadIdx.x;   // NE*16 threads
    int e = t >> 4, part = t & 15;
    if (e >= NE) return;
    const float4* p = (const float4*)(efeat + (size_t)e * 128 + part * 8);
    float4 a = p[0], b = p[1];
    uint4 u;
    u.x = pack2bf(a.x, a.y); u.y = pack2bf(a.z, a.w);
    u.z = pack2bf(b.x, b.y); u.w = pack2bf(b.z, b.w);
    *(uint4*)(eab + (size_t)e * 192 + 64 + part * 8) = u;
}

// ---------------------------------------------------------------------------
// Node projections, pure-bf16 MFMA GEMM with global_load_lds staging.
// C = Xb @ Wb^T (+bias). blockIdx.y = ct: mat = ct>>1, half = ct&1.
// 128x128 tile, BK=64, 4 waves 2x2, 4x4 16x16x32 frags, 2 k-steps per stage.
// ---------------------------------------------------------------------------
__global__ __launch_bounds__(256)
void node_gemm_kernel(const unsigned short* __restrict__ Xb,
                      const unsigned short* __restrict__ Wqb,
                      const unsigned short* __restrict__ Wkb,
                      const unsigned short* __restrict__ Wvb,
                      const unsigned short* __restrict__ Wsb,
                      const float* __restrict__ bq, const float* __restrict__ bk,
                      const float* __restrict__ bv, const float* __restrict__ bs,
                      unsigned short* __restrict__ qb,
                      unsigned short* __restrict__ kb,
                      unsigned short* __restrict__ vb,
                      float* __restrict__ outS)
{
    const int m0  = blockIdx.x * 128;
    const int ct  = blockIdx.y;
    const int mat = ct >> 1, half = ct & 1;
    const int colbase = half * 128;

    const unsigned short* __restrict__ W;
    const float* __restrict__ bias;
    switch (mat) {
        case 0:  W = Wqb; bias = bq; break;
        case 1:  W = Wkb; bias = bk; break;
        case 2:  W = Wvb; bias = bv; break;
        default: W = Wsb; bias = bs; break;
    }
    W += (size_t)colbase * 256;

    __shared__ __align__(16) unsigned char smem[32768];
    short* sA = (short*)smem;             // [128][64]
    short* sB = (short*)(smem + 16384);   // [128][64]

    const int tid  = threadIdx.x;
    const int lane = tid & 63;
    const int wave = tid >> 6;
    const int wm   = (wave & 1) * 64;
    const int wn   = (wave >> 1) * 64;
    const int lr   = lane & 15;
    const int lq   = lane >> 4;

    // staging address pieces: 8 lanes/row, 16B/lane
    const int srow = tid >> 3;            // 0..31 (row within 32-row pass)
    const int scol = (tid & 7) * 8;       // short offset within 64-col slice

    floatx4 acc[4][4];
    #pragma unroll
    for (int i = 0; i < 4; ++i)
        #pragma unroll
        for (int j = 0; j < 4; ++j)
            acc[i][j] = (floatx4){0.f, 0.f, 0.f, 0.f};

    for (int k0 = 0; k0 < 256; k0 += 64) {
        #pragma unroll
        for (int p = 0; p < 4; ++p) {
            int arow = m0 + p * 32 + srow;
            if (arow > NN - 1) arow = NN - 1;             // clamp, masked later
            gload_lds16(Xb + (size_t)arow * 256 + k0 + scol,
                        (char*)sA + p * 4096 + wave * 1024);
            gload_lds16(W + (size_t)(p * 32 + srow) * 256 + k0 + scol,
                        (char*)sB + p * 4096 + wave * 1024);
        }
        __syncthreads();

        #pragma unroll
        for (int ks = 0; ks < 2; ++ks) {
            bf16x8 af[4], bfr[4];
            #pragma unroll
            for (int i = 0; i < 4; ++i)
                af[i] = *(const bf16x8*)&sA[(wm + i * 16 + lr) * 64 + ks * 32 + lq * 8];
            #pragma unroll
            for (int j = 0; j < 4; ++j)
                bfr[j] = *(const bf16x8*)&sB[(wn + j * 16 + lr) * 64 + ks * 32 + lq * 8];
            #pragma unroll
            for (int i = 0; i < 4; ++i)
                #pragma unroll
                for (int j = 0; j < 4; ++j)
                    acc[i][j] = __builtin_amdgcn_mfma_f32_16x16x32_bf16(
                        af[i], bfr[j], acc[i][j], 0, 0, 0);
        }
        __syncthreads();
    }

    if (mat < 3) {
        unsigned short* __restrict__ Cb = (mat == 0) ? qb : (mat == 1) ? kb : vb;
        unsigned short* sOut = (unsigned short*)smem;   // [32][136]
        for (int ch = 0; ch < 4; ++ch) {
            __syncthreads();
            if ((ch >> 1) == (wave & 1)) {
                int ibase = (ch & 1) * 2;
                #pragma unroll
                for (int ii = 0; ii < 2; ++ii) {
                    int i = ibase + ii;
                    #pragma unroll
                    for (int j = 0; j < 4; ++j) {
                        int col = wn + j * 16 + lr;
                        float bb = bias[colbase + col];
                        #pragma unroll
                        for (int r = 0; r < 4; ++r) {
                            int rowc = ii * 16 + lq * 4 + r;
                            sOut[rowc * 136 + col] = f2bf(acc[i][j][r] + bb);
                        }
                    }
                }
            }
            __syncthreads();
            #pragma unroll
            for (int p = 0; p < 2; ++p) {
                int rowc = p * 16 + (tid >> 4);
                int off  = (tid & 15) * 8;
                int grow = m0 + ch * 32 + rowc;
                if (grow < NN) {
                    uint4 u = *(const uint4*)&sOut[rowc * 136 + off];
                    *(uint4*)&Cb[(size_t)grow * 256 + colbase + off] = u;
                }
            }
        }
    } else {
        float* sOutF = (float*)smem;    // [16][132]
        for (int ch = 0; ch < 8; ++ch) {
            __syncthreads();
            if ((ch >> 2) == (wave & 1)) {
                int i = ch & 3;
                #pragma unroll
                for (int j = 0; j < 4; ++j) {
                    int col = wn + j * 16 + lr;
                    float bb = bias[colbase + col];
                    #pragma unroll
                    for (int r = 0; r < 4; ++r) {
                        int rowc = lq * 4 + r;
                        sOutF[rowc * 132 + col] = acc[i][j][r] + bb;
                    }
                }
            }
            __syncthreads();
            #pragma unroll
            for (int p = 0; p < 2; ++p) {
                int rowc = p * 8 + (tid >> 5);
                int off  = (tid & 31) * 4;
                int grow = m0 + ch * 16 + rowc;
                if (grow < NN) {
                    float4 f = *(const float4*)&sOutF[rowc * 132 + off];
                    *(float4*)&outS[(size_t)grow * 256 + colbase + off] = f;
                }
            }
        }
    }
}

// ---------------------------------------------------------------------------
// Edge projection, pure-bf16 MFMA GEMM: epb = eab @ Web^T. K=192, BK=64.
// ---------------------------------------------------------------------------
__global__ __launch_bounds__(256)
void edge_gemm_kernel(const unsigned short* __restrict__ eab,
                      const unsigned short* __restrict__ Web,
                      unsigned short* __restrict__ epb)
{
    const int m0 = blockIdx.x * 128;
    const int n0 = blockIdx.y * 128;

    __shared__ __align__(16) unsigned char smem[32768];
    short* sA = (short*)smem;
    short* sB = (short*)(smem + 16384);

    const int tid  = threadIdx.x;
    const int lane = tid & 63;
    const int wave = tid >> 6;
    const int wm   = (wave & 1) * 64;
    const int wn   = (wave >> 1) * 64;
    const int lr   = lane & 15;
    const int lq   = lane >> 4;

    const int srow = tid >> 3;
    const int scol = (tid & 7) * 8;

    floatx4 acc[4][4];
    #pragma unroll
    for (int i = 0; i < 4; ++i)
        #pragma unroll
        for (int j = 0; j < 4; ++j)
            acc[i][j] = (floatx4){0.f, 0.f, 0.f, 0.f};

    for (int k0 = 0; k0 < 192; k0 += 64) {
        #pragma unroll
        for (int p = 0; p < 4; ++p) {
            gload_lds16(eab + (size_t)(m0 + p * 32 + srow) * 192 + k0 + scol,
                        (char*)sA + p * 4096 + wave * 1024);
            gload_lds16(Web + (size_t)(n0 + p * 32 + srow) * 192 + k0 + scol,
                        (char*)sB + p * 4096 + wave * 1024);
        }
        __syncthreads();

        #pragma unroll
        for (int ks = 0; ks < 2; ++ks) {
            bf16x8 af[4], bfr[4];
            #pragma unroll
            for (int i = 0; i < 4; ++i)
                af[i] = *(const bf16x8*)&sA[(wm + i * 16 + lr) * 64 + ks * 32 + lq * 8];
            #pragma unroll
            for (int j = 0; j < 4; ++j)
                bfr[j] = *(const bf16x8*)&sB[(wn + j * 16 + lr) * 64 + ks * 32 + lq * 8];
            #pragma unroll
            for (int i = 0; i < 4; ++i)
                #pragma unroll
                for (int j = 0; j < 4; ++j)
                    acc[i][j] = __builtin_amdgcn_mfma_f32_16x16x32_bf16(
                        af[i], bfr[j], acc[i][j], 0, 0, 0);
        }
        __syncthreads();
    }

    unsigned short* sOut = (unsigned short*)smem;   // [32][136]
    for (int ch = 0; ch < 4; ++ch) {
        __syncthreads();
        if ((ch >> 1) == (wave & 1)) {
            int ibase = (ch & 1) * 2;
            #pragma unroll
            for (int ii = 0; ii < 2; ++ii) {
                int i = ibase + ii;
                #pragma unroll
                for (int j = 0; j < 4; ++j) {
                    int col = wn + j * 16 + lr;
                    #pragma unroll
                    for (int r = 0; r < 4; ++r) {
                        int rowc = ii * 16 + lq * 4 + r;
                        sOut[rowc * 136 + col] = f2bf(acc[i][j][r]);
                    }
                }
            }
        }
        __syncthreads();
        #pragma unroll
        for (int p = 0; p < 2; ++p) {
            int rowc = p * 16 + (tid >> 4);
            int off  = (tid & 15) * 8;
            int grow = m0 + ch * 32 + rowc;
            uint4 u = *(const uint4*)&sOut[rowc * 136 + off];
            *(uint4*)&epb[(size_t)grow * 256 + n0 + off] = u;
        }
    }
}

// ---------------------------------------------------------------------------
// CSR build: histogram, single-block scan, scatter (pre-gathers src).
// ---------------------------------------------------------------------------
__global__ __launch_bounds__(256)
void deg_kernel(const int* __restrict__ et, int* __restrict__ deg)
{
    int e = blockIdx.x * 256 + threadIdx.x;
    if (e < NE) atomicAdd(&deg[et[NE + e]], 1);
}

__global__ __launch_bounds__(1024)
void scan_kernel(const int* __restrict__ deg,
                 int* __restrict__ rowstart, int* __restrict__ cursor)
{
    __shared__ int sums[1024];
    const int T  = 1024;
    const int CH = (NN + T - 1) / T;
    const int t    = threadIdx.x;
    const int base = t * CH;

    int s = 0;
    for (int i = 0; i < CH; ++i) {
        int idx = base + i;
        if (idx < NN) s += deg[idx];
    }
    sums[t] = s;
    __syncthreads();
    for (int off = 1; off < T; off <<= 1) {
        int v = (t >= off) ? sums[t - off] : 0;
        __syncthreads();
        sums[t] += v;
        __syncthreads();
    }
    int run = (t == 0) ? 0 : sums[t - 1];
    for (int i = 0; i < CH; ++i) {
        int idx = base + i;
        if (idx < NN) {
            rowstart[idx] = run;
            cursor[idx]   = run;
            run += deg[idx];
        }
    }
    if (t == T - 1) rowstart[NN] = run;
}

__global__ __launch_bounds__(256)
void scatter_kernel(const int* __restrict__ et,
                    int* __restrict__ cursor,
                    int* __restrict__ elist, int* __restrict__ slist)
{
    int e = blockIdx.x * 256 + threadIdx.x;
    if (e < NE) {
        int d   = et[NE + e];
        int pos = atomicAdd(&cursor[d], 1);
        elist[pos] = e;
        slist[pos] = et[e];
    }
}

// ---------------------------------------------------------------------------
// Fused attention + aggregation + skip: one wave per dst node, bf16 gathers.
// ---------------------------------------------------------------------------
__global__ __launch_bounds__(256)
void fused_agg_kernel(const int* __restrict__ slist,
                      const int* __restrict__ rowstart,
                      const int* __restrict__ elist,
                      const unsigned short* __restrict__ qb,
                      const unsigned short* __restrict__ kb,
                      const unsigned short* __restrict__ vb,
                      const unsigned short* __restrict__ epb,
                      float* __restrict__ out)
{
    const int n = blockIdx.x * 4 + (threadIdx.x >> 6);
    if (n >= NN) return;
    const int lane = threadIdx.x & 63;

    ushort4 qu = *(const ushort4*)(qb + (size_t)n * 256 + lane * 4);
    const float q0 = bf2f(qu.x), q1 = bf2f(qu.y), q2 = bf2f(qu.z), q3 = bf2f(qu.w);

    float acc0 = 0.f, acc1 = 0.f, acc2 = 0.f, acc3 = 0.f, accd = 0.f;

    const int s0 = rowstart[n];
    const int s1 = rowstart[n + 1];

    for (int i = s0; i < s1; ++i) {
        const int e   = elist[i];
        const int src = slist[i];
        ushort4 ku = *(const ushort4*)(kb  + (size_t)src * 256 + lane * 4);
        ushort4 pu = *(const ushort4*)(epb + (size_t)e   * 256 + lane * 4);
        ushort4 vu = *(const ushort4*)(vb  + (size_t)src * 256 + lane * 4);

        float kp0 = bf2f(ku.x) + bf2f(pu.x);
        float kp1 = bf2f(ku.y) + bf2f(pu.y);
        float kp2 = bf2f(ku.z) + bf2f(pu.z);
        float kp3 = bf2f(ku.w) + bf2f(pu.w);

        float part = q0 * kp0 + q1 * kp1 + q2 * kp2 + q3 * kp3;
        part += __shfl_xor(part, 1);
        part += __shfl_xor(part, 2);
        part += __shfl_xor(part, 4);

        float eav = __expf(part * 0.17677669529663687f);  // 1/sqrt(32)
        acc0 = fmaf(eav, bf2f(vu.x) + bf2f(pu.x), acc0);
        acc1 = fmaf(eav, bf2f(vu.y) + bf2f(pu.y), acc1);
        acc2 = fmaf(eav, bf2f(vu.z) + bf2f(pu.z), acc2);
        acc3 = fmaf(eav, bf2f(vu.w) + bf2f(pu.w), acc3);
        accd += eav;
    }

    const float inv = 1.f / (accd + 1e-16f);
    float* po = out + (size_t)n * 256 + lane * 4;
    float4 o = *(const float4*)po;
    o.x = fmaf(acc0, inv, o.x);
    o.y = fmaf(acc1, inv, o.y);
    o.z = fmaf(acc2, inv, o.z);
    o.w = fmaf(acc3, inv, o.w);
    *(float4*)po = o;
}

// ---------------------------------------------------------------------------
extern "C" void kernel_launch(void* const* d_in, const int* in_sizes, int n_in,
                              void* d_out, int out_size, void* d_ws, size_t ws_size,
                              hipStream_t stream)
{
    const int*   et  = (const int*)  d_in[0];
    const float* ef  = (const float*)d_in[1];
    const float* tv  = (const float*)d_in[2];
    const float* nf  = (const float*)d_in[3];
    const float* w_t = (const float*)d_in[4];
    const float* b_t = (const float*)d_in[5];
    const float* Wq  = (const float*)d_in[6];
    const float* bq  = (const float*)d_in[7];
    const float* Wk  = (const float*)d_in[8];
    const float* bk  = (const float*)d_in[9];
    const float* Wv  = (const float*)d_in[10];
    const float* bv  = (const float*)d_in[11];
    const float* We  = (const float*)d_in[12];
    const float* Ws  = (const float*)d_in[13];
    const float* bs  = (const float*)d_in[14];
    float* out = (float*)d_out;

    // ws layout (bf16 buffers then ints)
    unsigned short* qb  = (unsigned short*)d_ws;
    unsigned short* kb  = qb  + (size_t)NN * 256;
    unsigned short* vb  = kb  + (size_t)NN * 256;
    unsigned short* epb = vb  + (size_t)NN * 256;
    unsigned short* nfb = epb + (size_t)NE * 256;
    unsigned short* eab = nfb + (size_t)NN * 256;
    unsigned short* Wqb = eab + (size_t)NE * 192;
    unsigned short* Wkb = Wqb + 65536;
    unsigned short* Wvb = Wkb + 65536;
    unsigned short* Wsb = Wvb + 65536;
    unsigned short* Web = Wsb + 65536;
    int* deg      = (int*)(Web + 49152);
    int* rowstart = deg + NN;
    int* cursor   = rowstart + NN + 1;
    int* elist    = cursor + NN;
    int* slist    = elist + NE;
    size_t need   = (size_t)((char*)(slist + NE) - (char*)d_ws);
    if (ws_size < need) return;

    hipMemsetAsync(deg, 0, (size_t)NN * sizeof(int), stream);

    // --- prep: bf16 conversions + e_attr materialization -------------------
    cvt_bf16_kernel<<<(NN * 256 / 8 + 255) / 256, 256, 0, stream>>>(nf, nfb, NN * 256 / 8);
    cvt_bf16_kernel<<<32, 256, 0, stream>>>(Wq, Wqb, 8192);
    cvt_bf16_kernel<<<32, 256, 0, stream>>>(Wk, Wkb, 8192);
    cvt_bf16_kernel<<<32, 256, 0, stream>>>(Wv, Wvb, 8192);
    cvt_bf16_kernel<<<32, 256, 0, stream>>>(Ws, Wsb, 8192);
    cvt_bf16_kernel<<<24, 256, 0, stream>>>(We, Web, 6144);
    tf_kernel<<<(NE * 8 + 255) / 256, 256, 0, stream>>>(tv, w_t, b_t, eab);
    efcvt_kernel<<<(NE * 16 + 255) / 256, 256, 0, stream>>>(ef, eab);

    // --- GEMMs -------------------------------------------------------------
    node_gemm_kernel<<<dim3((NN + 127) / 128, 8), 256, 0, stream>>>(
        nfb, Wqb, Wkb, Wvb, Wsb, bq, bk, bv, bs, qb, kb, vb, out);

    edge_gemm_kernel<<<dim3(NE / 128, 2), 256, 0, stream>>>(eab, Web, epb);

    // --- CSR + fused attention/aggregation ---------------------------------
    deg_kernel<<<(NE + 255) / 256, 256, 0, stream>>>(et, deg);
    scan_kernel<<<1, 1024, 0, stream>>>(deg, rowstart, cursor);
    scatter_kernel<<<(NE + 255) / 256, 256, 0, stream>>>(et, cursor, elist, slist);

    fused_agg_kernel<<<(NN + 3) / 4, 256, 0, stream>>>(
        slist, rowstart, elist, qb, kb, vb, epb, out);
}